// Round 3
// baseline (1303.077 us; speedup 1.0000x reference)
//
#include <hip/hip_runtime.h>
#include <hip/hip_bf16.h>

#define D 16

// ---------------- Kernel A: q,v per node (packed [n][32]: q | v) ----------------
__global__ void node_prep_qv(const float* __restrict__ x,
                             const float* __restrict__ Wq, const float* __restrict__ bq,
                             const float* __restrict__ Wv, const float* __restrict__ bv,
                             float* __restrict__ qv, int n_nodes) {
    __shared__ float sWq[D * D], sWv[D * D], sb[2 * D];
    for (int i = threadIdx.x; i < D * D; i += blockDim.x) { sWq[i] = Wq[i]; sWv[i] = Wv[i]; }
    if (threadIdx.x < D) { sb[threadIdx.x] = bq[threadIdx.x]; sb[D + threadIdx.x] = bv[threadIdx.x]; }
    __syncthreads();
    int n = blockIdx.x * blockDim.x + threadIdx.x;
    if (n >= n_nodes) return;
    float xr[D];
    const float4* xp = (const float4*)(x + (size_t)n * D);
#pragma unroll
    for (int i = 0; i < 4; i++) {
        float4 t = xp[i];
        xr[4*i] = t.x; xr[4*i+1] = t.y; xr[4*i+2] = t.z; xr[4*i+3] = t.w;
    }
    float qr[D], vr[D];
#pragma unroll
    for (int c = 0; c < D; c++) { qr[c] = sb[c]; vr[c] = sb[D + c]; }
#pragma unroll
    for (int j = 0; j < D; j++) {
        float xj = xr[j];
#pragma unroll
        for (int c = 0; c < D; c++) {
            qr[c] = fmaf(xj, sWq[j * D + c], qr[c]);
            vr[c] = fmaf(xj, sWv[j * D + c], vr[c]);
        }
    }
    float4* qp = (float4*)(qv + (size_t)n * 32);
    float4* vp = (float4*)(qv + (size_t)n * 32 + D);
#pragma unroll
    for (int i = 0; i < 4; i++) {
        qp[i] = make_float4(qr[4*i], qr[4*i+1], qr[4*i+2], qr[4*i+3]);
        vp[i] = make_float4(vr[4*i], vr[4*i+1], vr[4*i+2], vr[4*i+3]);
    }
}

// ---------------- CSR build ----------------
__global__ void hist_tgt(const int* __restrict__ ei, int* __restrict__ counts, int n_edges) {
    int e = blockIdx.x * blockDim.x + threadIdx.x;
    if (e >= n_edges) return;
    atomicAdd(&counts[ei[(size_t)n_edges + e]], 1);
}

#define SCAN_B 512
__global__ void scan1(const int* __restrict__ counts, int* __restrict__ rowptr,
                      int* __restrict__ bsum, int n) {
    __shared__ int tmp[SCAN_B];
    int i = blockIdx.x * SCAN_B + threadIdx.x;
    int v = (i < n) ? counts[i] : 0;
    tmp[threadIdx.x] = v;
    __syncthreads();
    for (int off = 1; off < SCAN_B; off <<= 1) {
        int t = (threadIdx.x >= off) ? tmp[threadIdx.x - off] : 0;
        __syncthreads();
        tmp[threadIdx.x] += t;
        __syncthreads();
    }
    if (i < n) rowptr[i] = tmp[threadIdx.x] - v;  // exclusive
    if (threadIdx.x == SCAN_B - 1) bsum[blockIdx.x] = tmp[threadIdx.x];
}

__global__ void scan2(int* __restrict__ bsum, int nb) {
    __shared__ int tmp[1024];
    int v = (threadIdx.x < nb) ? bsum[threadIdx.x] : 0;
    tmp[threadIdx.x] = v;
    __syncthreads();
    for (int off = 1; off < 1024; off <<= 1) {
        int t = (threadIdx.x >= off) ? tmp[threadIdx.x - off] : 0;
        __syncthreads();
        tmp[threadIdx.x] += t;
        __syncthreads();
    }
    if (threadIdx.x < nb) bsum[threadIdx.x] = tmp[threadIdx.x] - v;  // exclusive
}

__global__ void scan3(int* __restrict__ rowptr, int* __restrict__ cursor,
                      const int* __restrict__ bsum, int n) {
    int i = blockIdx.x * blockDim.x + threadIdx.x;
    if (i >= n) return;
    int r = rowptr[i] + bsum[i / SCAN_B];
    rowptr[i] = r;
    cursor[i] = r;
}

__global__ void scatter_edges(const int* __restrict__ ei, int* __restrict__ cursor,
                              int* __restrict__ rec, int n_edges) {
    int e = blockIdx.x * blockDim.x + threadIdx.x;
    if (e >= n_edges) return;
    int tgt = ei[(size_t)n_edges + e];
    int pos = atomicAdd(&cursor[tgt], 1);
    rec[pos] = e;  // edge id; src re-read from ei in gather
}

// ---------------- Gather + message + aggregate + skip (NO atomics) ----------------
// 16 lanes per node; lane c owns channel c.
__global__ void gather_compute(const float* __restrict__ x,
                               const int* __restrict__ ei,
                               const float* __restrict__ ea,
                               const float* __restrict__ qv,
                               const int* __restrict__ rowptr,
                               const int* __restrict__ counts,
                               const int* __restrict__ rec,
                               const float* __restrict__ We,
                               const float* __restrict__ Wk, const float* __restrict__ bk,
                               const float* __restrict__ Ws, const float* __restrict__ bs,
                               const float* __restrict__ bias,
                               float* __restrict__ h, int n_nodes) {
    __shared__ float sWe[D * D], sWk[D * D], sWs[D * D], sb[2 * D];
    for (int i = threadIdx.x; i < D * D; i += blockDim.x) {
        sWe[i] = We[i]; sWk[i] = Wk[i]; sWs[i] = Ws[i];
    }
    if (threadIdx.x < D) {
        sb[threadIdx.x]     = bk[threadIdx.x];
        sb[D + threadIdx.x] = bs[threadIdx.x] + bias[threadIdx.x];
    }
    __syncthreads();

    int g = threadIdx.x >> 4;
    int c = threadIdx.x & (D - 1);
    int node = blockIdx.x * 16 + g;
    if (node >= n_nodes) return;

    // k[node] and skip term from x[node] (coalesced 64B per group)
    float xc = x[(size_t)node * D + c];
    float kk = sb[c], hh = sb[D + c];
#pragma unroll
    for (int j = 0; j < D; j++) {
        float xj = __shfl(xc, j, D);
        kk = fmaf(xj, sWk[j * D + c], kk);
        hh = fmaf(xj, sWs[j * D + c], hh);
    }

    int start = rowptr[node];
    int deg = counts[node];
    float acc = 0.f;
    for (int t = 0; t < deg; ++t) {
        int eidx = rec[start + t];                 // broadcast within group
        int src = ei[eidx];                        // broadcast
        float eac = __builtin_nontemporal_load(&ea[(size_t)eidx * D + c]);  // 64B line
        float qq = qv[(size_t)src * 32 + c];       // 128B line (q|v)
        float vv = qv[(size_t)src * 32 + D + c];
        float ee = 0.f;
#pragma unroll
        for (int j = 0; j < D; j++)
            ee = fmaf(__shfl(eac, j, D), sWe[j * D + c], ee);
        float z = kk + ee + qq;
        acc = fmaf(vv, 1.f / (1.f + __expf(-z)), acc);
    }
    h[(size_t)node * D + c] = acc + hh;
}

// ---------------- BN statistics ----------------
__global__ void bn_stats(const float* __restrict__ h, float* __restrict__ stats, int n_nodes) {
    float s = 0.f, ss = 0.f;
    size_t total = (size_t)n_nodes * D;
    size_t stride = (size_t)gridDim.x * blockDim.x;
    for (size_t i = (size_t)blockIdx.x * blockDim.x + threadIdx.x; i < total; i += stride) {
        float val = h[i];
        s += val;
        ss = fmaf(val, val, ss);
    }
    s += __shfl_xor(s, 16); s += __shfl_xor(s, 32);
    ss += __shfl_xor(ss, 16); ss += __shfl_xor(ss, 32);
    __shared__ float ls[4 * D], lss[4 * D];
    int wave = threadIdx.x >> 6, lane = threadIdx.x & 63;
    if (lane < D) { ls[wave * D + lane] = s; lss[wave * D + lane] = ss; }
    __syncthreads();
    if (threadIdx.x < D) {
        float ts = 0.f, tss = 0.f;
#pragma unroll
        for (int w = 0; w < 4; w++) { ts += ls[w * D + threadIdx.x]; tss += lss[w * D + threadIdx.x]; }
        atomicAdd(&stats[threadIdx.x], ts);
        atomicAdd(&stats[D + threadIdx.x], tss);
    }
}

// ---------------- normalize + ReLU + residual ----------------
__global__ void bn_finalize(const float* __restrict__ x, const float* __restrict__ stats,
                            const float* __restrict__ gamma, const float* __restrict__ beta,
                            float* __restrict__ out, int n_nodes) {
    __shared__ float sc[D], sh[D];
    if (threadIdx.x < D) {
        float inv_n = 1.f / (float)n_nodes;
        float mean = stats[threadIdx.x] * inv_n;
        float var = stats[D + threadIdx.x] * inv_n - mean * mean;
        float inv = rsqrtf(var + 1e-5f);
        float g = gamma[threadIdx.x] * inv;
        sc[threadIdx.x] = g;
        sh[threadIdx.x] = beta[threadIdx.x] - mean * g;
    }
    __syncthreads();
    size_t i = (size_t)blockIdx.x * blockDim.x + threadIdx.x;
    size_t total = (size_t)n_nodes * D;
    if (i >= total) return;
    int c = (int)(i & (D - 1));
    float t = fmaf(out[i], sc[c], sh[c]);
    out[i] = x[i] + fmaxf(t, 0.f);
}

extern "C" void kernel_launch(void* const* d_in, const int* in_sizes, int n_in,
                              void* d_out, int out_size, void* d_ws, size_t ws_size,
                              hipStream_t stream) {
    const float* x     = (const float*)d_in[0];
    const int*   ei    = (const int*)d_in[1];
    const float* ea    = (const float*)d_in[2];
    const float* Wk    = (const float*)d_in[3];
    const float* bk    = (const float*)d_in[4];
    const float* Wq    = (const float*)d_in[5];
    const float* bq    = (const float*)d_in[6];
    const float* Wv    = (const float*)d_in[7];
    const float* bv    = (const float*)d_in[8];
    const float* We    = (const float*)d_in[9];
    const float* Ws    = (const float*)d_in[10];
    const float* bs    = (const float*)d_in[11];
    const float* bias  = (const float*)d_in[12];
    const float* gamma = (const float*)d_in[13];
    const float* beta  = (const float*)d_in[14];

    int n_nodes = in_sizes[0] / D;
    int n_edges = in_sizes[1] / 2;
    float* out = (float*)d_out;
    float* ws  = (float*)d_ws;

    // Workspace layout (~90 MB)
    float* qv    = ws;                                  // n_nodes*32 floats
    int*   counts = (int*)(qv + (size_t)n_nodes * 32);  // n_nodes
    int*   rowptr = counts + n_nodes;                   // n_nodes
    int*   cursor = rowptr + n_nodes;                   // n_nodes
    int*   bsum   = cursor + n_nodes;                   // 1024
    int*   rec    = bsum + 1024;                        // n_edges
    float* stats  = (float*)(rec + n_edges);            // 32

    hipMemsetAsync(counts, 0, (size_t)n_nodes * sizeof(int), stream);
    hipMemsetAsync(stats, 0, 2 * D * sizeof(float), stream);

    int nb_nodes = (n_nodes + 255) / 256;
    int nb_edges = (n_edges + 255) / 256;
    int nb_scan = (n_nodes + SCAN_B - 1) / SCAN_B;

    node_prep_qv<<<nb_nodes, 256, 0, stream>>>(x, Wq, bq, Wv, bv, qv, n_nodes);
    hist_tgt<<<nb_edges, 256, 0, stream>>>(ei, counts, n_edges);
    scan1<<<nb_scan, SCAN_B, 0, stream>>>(counts, rowptr, bsum, n_nodes);
    scan2<<<1, 1024, 0, stream>>>(bsum, nb_scan);
    scan3<<<nb_nodes, 256, 0, stream>>>(rowptr, cursor, bsum, n_nodes);
    scatter_edges<<<nb_edges, 256, 0, stream>>>(ei, cursor, rec, n_edges);

    int nb_gather = (n_nodes + 15) / 16;
    gather_compute<<<nb_gather, 256, 0, stream>>>(x, ei, ea, qv, rowptr, counts, rec,
                                                  We, Wk, bk, Ws, bs, bias, out, n_nodes);

    bn_stats<<<2048, 256, 0, stream>>>(out, stats, n_nodes);

    size_t total = (size_t)n_nodes * D;
    int nb_fin = (int)((total + 255) / 256);
    bn_finalize<<<nb_fin, 256, 0, stream>>>(x, stats, gamma, beta, out, n_nodes);
}

// Round 4
// 555.230 us; speedup vs baseline: 2.3469x; 2.3469x over previous
//
#include <hip/hip_runtime.h>
#include <hip/hip_bf16.h>
#include <hip/hip_fp16.h>

#define D 16

// Workspace layout (64MB + 128B, well under proven >=96MB):
//   qv_h [n][32] f16 : q | v        (32 MB)   gathered by src, one 64B line
//   k_h  [n][16] f16 : k            (16 MB)   gathered by tgt, 32B
//   hagg [n][16] f16 : message acc  (16 MB)   pk_add_f16 atomics, 2ch/op
//   stats[32] f32

// ---------------- Kernel A: per-node linears ----------------
__global__ void node_prep(const float* __restrict__ x,
                          const float* __restrict__ Wk, const float* __restrict__ bk,
                          const float* __restrict__ Wq, const float* __restrict__ bq,
                          const float* __restrict__ Wv, const float* __restrict__ bv,
                          const float* __restrict__ Ws, const float* __restrict__ bs,
                          const float* __restrict__ bias,
                          __half* __restrict__ k_h, __half* __restrict__ qv_h,
                          float* __restrict__ skip, int n_nodes) {
    __shared__ float sWk[D * D], sWq[D * D], sWv[D * D], sWs[D * D], sb[4 * D];
    for (int i = threadIdx.x; i < D * D; i += blockDim.x) {
        sWk[i] = Wk[i]; sWq[i] = Wq[i]; sWv[i] = Wv[i]; sWs[i] = Ws[i];
    }
    if (threadIdx.x < D) {
        sb[threadIdx.x]         = bk[threadIdx.x];
        sb[D + threadIdx.x]     = bq[threadIdx.x];
        sb[2 * D + threadIdx.x] = bv[threadIdx.x];
        sb[3 * D + threadIdx.x] = bs[threadIdx.x] + bias[threadIdx.x];
    }
    __syncthreads();
    int n = blockIdx.x * blockDim.x + threadIdx.x;
    if (n >= n_nodes) return;

    float xr[D];
    const float4* xp = (const float4*)(x + (size_t)n * D);
#pragma unroll
    for (int i = 0; i < 4; i++) {
        float4 t = xp[i];
        xr[4*i] = t.x; xr[4*i+1] = t.y; xr[4*i+2] = t.z; xr[4*i+3] = t.w;
    }
    float kr[D], qr[D], vr[D], hr[D];
#pragma unroll
    for (int c = 0; c < D; c++) {
        kr[c] = sb[c]; qr[c] = sb[D + c]; vr[c] = sb[2*D + c]; hr[c] = sb[3*D + c];
    }
#pragma unroll
    for (int j = 0; j < D; j++) {
        float xj = xr[j];
#pragma unroll
        for (int c = 0; c < D; c++) {
            kr[c] = fmaf(xj, sWk[j * D + c], kr[c]);
            qr[c] = fmaf(xj, sWq[j * D + c], qr[c]);
            vr[c] = fmaf(xj, sWv[j * D + c], vr[c]);
            hr[c] = fmaf(xj, sWs[j * D + c], hr[c]);
        }
    }
    // k row: 16 f16 = 32B
    __align__(16) __half2 kp[8];
#pragma unroll
    for (int i = 0; i < 8; i++) kp[i] = __floats2half2_rn(kr[2*i], kr[2*i+1]);
    float4* kd = (float4*)(k_h + (size_t)n * D);
    kd[0] = *(float4*)&kp[0];
    kd[1] = *(float4*)&kp[4];
    // qv row: 32 f16 = 64B
    __align__(16) __half2 qp[16];
#pragma unroll
    for (int i = 0; i < 8; i++) qp[i]     = __floats2half2_rn(qr[2*i], qr[2*i+1]);
#pragma unroll
    for (int i = 0; i < 8; i++) qp[8 + i] = __floats2half2_rn(vr[2*i], vr[2*i+1]);
    float4* qd = (float4*)(qv_h + (size_t)n * 32);
#pragma unroll
    for (int i = 0; i < 4; i++) qd[i] = *(float4*)&qp[4*i];
    // skip -> d_out (fp32)
    float4* sp = (float4*)(skip + (size_t)n * D);
#pragma unroll
    for (int i = 0; i < 4; i++)
        sp[i] = make_float4(hr[4*i], hr[4*i+1], hr[4*i+2], hr[4*i+3]);
}

// ---------------- Kernel B: per-edge gated message, pk_add_f16 scatter ----------------
// 16 lanes per edge; lane c owns channel c; even lanes issue the packed atomic.
__global__ void edge_msg(const int* __restrict__ ei, const float* __restrict__ ea,
                         const float* __restrict__ We,
                         const __half* __restrict__ k_h,
                         const __half* __restrict__ qv_h,
                         __half* __restrict__ hagg, int n_edges) {
    __shared__ float sWe[D * D];
    for (int i = threadIdx.x; i < D * D; i += blockDim.x) sWe[i] = We[i];
    __syncthreads();

    long long gid = (long long)blockIdx.x * blockDim.x + threadIdx.x;
    long long edge = gid >> 4;
    int c = (int)(gid & (D - 1));
    if (edge >= n_edges) return;

    int src = __builtin_nontemporal_load(&ei[edge]);
    int tgt = __builtin_nontemporal_load(&ei[(size_t)n_edges + edge]);

    float eac = __builtin_nontemporal_load(&ea[(size_t)edge * D + c]);
    float ec = 0.f;
#pragma unroll
    for (int j = 0; j < D; j++)
        ec = fmaf(__shfl(eac, j, D), sWe[j * D + c], ec);

    float kk = __half2float(k_h[(size_t)tgt * D + c]);
    float qq = __half2float(qv_h[(size_t)src * 32 + c]);
    float vv = __half2float(qv_h[(size_t)src * 32 + D + c]);
    float z = kk + ec + qq;
    float msg = vv / (1.f + __expf(-z));

    float partner = __shfl_xor(msg, 1);  // lane c<->c^1
    if ((c & 1) == 0) {
        __half2 m2 = __floats2half2_rn(msg, partner);  // (c, c+1)
        unsafeAtomicAdd((__half2*)&hagg[(size_t)tgt * D + c], m2);
    }
}

// ---------------- Kernel C: BN statistics ----------------
__global__ void bn_stats(const float* __restrict__ skip, const __half* __restrict__ hagg,
                         float* __restrict__ stats, int n_nodes) {
    float s = 0.f, ss = 0.f;
    size_t total = (size_t)n_nodes * D;
    size_t stride = (size_t)gridDim.x * blockDim.x;
    for (size_t i = (size_t)blockIdx.x * blockDim.x + threadIdx.x; i < total; i += stride) {
        float val = skip[i] + __half2float(hagg[i]);
        s += val;
        ss = fmaf(val, val, ss);
    }
    s += __shfl_xor(s, 16); s += __shfl_xor(s, 32);
    ss += __shfl_xor(ss, 16); ss += __shfl_xor(ss, 32);
    __shared__ float ls[4 * D], lss[4 * D];
    int wave = threadIdx.x >> 6, lane = threadIdx.x & 63;
    if (lane < D) { ls[wave * D + lane] = s; lss[wave * D + lane] = ss; }
    __syncthreads();
    if (threadIdx.x < D) {
        float ts = 0.f, tss = 0.f;
#pragma unroll
        for (int w = 0; w < 4; w++) { ts += ls[w * D + threadIdx.x]; tss += lss[w * D + threadIdx.x]; }
        atomicAdd(&stats[threadIdx.x], ts);
        atomicAdd(&stats[D + threadIdx.x], tss);
    }
}

// ---------------- Kernel D: normalize + ReLU + residual ----------------
__global__ void bn_finalize(const float* __restrict__ x, const __half* __restrict__ hagg,
                            const float* __restrict__ stats,
                            const float* __restrict__ gamma, const float* __restrict__ beta,
                            float* __restrict__ out, int n_nodes) {
    __shared__ float sc[D], sh[D];
    if (threadIdx.x < D) {
        float inv_n = 1.f / (float)n_nodes;
        float mean = stats[threadIdx.x] * inv_n;
        float var = stats[D + threadIdx.x] * inv_n - mean * mean;
        float inv = rsqrtf(var + 1e-5f);
        float g = gamma[threadIdx.x] * inv;
        sc[threadIdx.x] = g;
        sh[threadIdx.x] = beta[threadIdx.x] - mean * g;
    }
    __syncthreads();
    size_t i = (size_t)blockIdx.x * blockDim.x + threadIdx.x;
    size_t total = (size_t)n_nodes * D;
    if (i >= total) return;
    int c = (int)(i & (D - 1));
    float h = out[i] + __half2float(hagg[i]);   // skip + aggregated messages
    float t = fmaf(h, sc[c], sh[c]);
    out[i] = x[i] + fmaxf(t, 0.f);
}

extern "C" void kernel_launch(void* const* d_in, const int* in_sizes, int n_in,
                              void* d_out, int out_size, void* d_ws, size_t ws_size,
                              hipStream_t stream) {
    const float* x     = (const float*)d_in[0];
    const int*   ei    = (const int*)d_in[1];
    const float* ea    = (const float*)d_in[2];
    const float* Wk    = (const float*)d_in[3];
    const float* bk    = (const float*)d_in[4];
    const float* Wq    = (const float*)d_in[5];
    const float* bq    = (const float*)d_in[6];
    const float* Wv    = (const float*)d_in[7];
    const float* bv    = (const float*)d_in[8];
    const float* We    = (const float*)d_in[9];
    const float* Ws    = (const float*)d_in[10];
    const float* bs    = (const float*)d_in[11];
    const float* bias  = (const float*)d_in[12];
    const float* gamma = (const float*)d_in[13];
    const float* beta  = (const float*)d_in[14];

    int n_nodes = in_sizes[0] / D;
    int n_edges = in_sizes[1] / 2;
    float* out = (float*)d_out;

    __half* qv_h = (__half*)d_ws;                       // n*32 f16 (32MB)
    __half* k_h  = qv_h + (size_t)n_nodes * 32;         // n*16 f16 (16MB)
    __half* hagg = k_h + (size_t)n_nodes * D;           // n*16 f16 (16MB)
    float* stats = (float*)(hagg + (size_t)n_nodes * D);

    hipMemsetAsync(hagg, 0, (size_t)n_nodes * D * sizeof(__half), stream);
    hipMemsetAsync(stats, 0, 2 * D * sizeof(float), stream);

    int nb_nodes = (n_nodes + 255) / 256;
    node_prep<<<nb_nodes, 256, 0, stream>>>(x, Wk, bk, Wq, bq, Wv, bv, Ws, bs, bias,
                                            k_h, qv_h, out, n_nodes);

    long long edge_threads = (long long)n_edges * D;
    int nb_edges = (int)((edge_threads + 255) / 256);
    edge_msg<<<nb_edges, 256, 0, stream>>>(ei, ea, We, k_h, qv_h, hagg, n_edges);

    bn_stats<<<2048, 256, 0, stream>>>(out, hagg, stats, n_nodes);

    size_t total = (size_t)n_nodes * D;
    int nb_fin = (int)((total + 255) / 256);
    bn_finalize<<<nb_fin, 256, 0, stream>>>(x, hagg, stats, gamma, beta, out, n_nodes);
}

// Round 6
// 508.711 us; speedup vs baseline: 2.5615x; 1.0914x over previous
//
#include <hip/hip_runtime.h>
#include <hip/hip_bf16.h>
#include <hip/hip_fp16.h>

#define D 16

typedef _Float16 f16x4 __attribute__((ext_vector_type(4)));
typedef float f32x4 __attribute__((ext_vector_type(4)));

// ---------------- Kernel A: per-node linears (same as R4) ----------------
__global__ void node_prep(const float* __restrict__ x,
                          const float* __restrict__ Wk, const float* __restrict__ bk,
                          const float* __restrict__ Wq, const float* __restrict__ bq,
                          const float* __restrict__ Wv, const float* __restrict__ bv,
                          const float* __restrict__ Ws, const float* __restrict__ bs,
                          const float* __restrict__ bias,
                          __half* __restrict__ k_h, __half* __restrict__ qv_h,
                          float* __restrict__ skip, int n_nodes) {
    __shared__ float sWk[D * D], sWq[D * D], sWv[D * D], sWs[D * D], sb[4 * D];
    for (int i = threadIdx.x; i < D * D; i += blockDim.x) {
        sWk[i] = Wk[i]; sWq[i] = Wq[i]; sWv[i] = Wv[i]; sWs[i] = Ws[i];
    }
    if (threadIdx.x < D) {
        sb[threadIdx.x]         = bk[threadIdx.x];
        sb[D + threadIdx.x]     = bq[threadIdx.x];
        sb[2 * D + threadIdx.x] = bv[threadIdx.x];
        sb[3 * D + threadIdx.x] = bs[threadIdx.x] + bias[threadIdx.x];
    }
    __syncthreads();
    int n = blockIdx.x * blockDim.x + threadIdx.x;
    if (n >= n_nodes) return;

    float xr[D];
    const float4* xp = (const float4*)(x + (size_t)n * D);
#pragma unroll
    for (int i = 0; i < 4; i++) {
        float4 t = xp[i];
        xr[4*i] = t.x; xr[4*i+1] = t.y; xr[4*i+2] = t.z; xr[4*i+3] = t.w;
    }
    float kr[D], qr[D], vr[D], hr[D];
#pragma unroll
    for (int c = 0; c < D; c++) {
        kr[c] = sb[c]; qr[c] = sb[D + c]; vr[c] = sb[2*D + c]; hr[c] = sb[3*D + c];
    }
#pragma unroll
    for (int j = 0; j < D; j++) {
        float xj = xr[j];
#pragma unroll
        for (int c = 0; c < D; c++) {
            kr[c] = fmaf(xj, sWk[j * D + c], kr[c]);
            qr[c] = fmaf(xj, sWq[j * D + c], qr[c]);
            vr[c] = fmaf(xj, sWv[j * D + c], vr[c]);
            hr[c] = fmaf(xj, sWs[j * D + c], hr[c]);
        }
    }
    __align__(16) __half2 kp[8];
#pragma unroll
    for (int i = 0; i < 8; i++) kp[i] = __floats2half2_rn(kr[2*i], kr[2*i+1]);
    float4* kd = (float4*)(k_h + (size_t)n * D);
    kd[0] = *(float4*)&kp[0];
    kd[1] = *(float4*)&kp[4];
    __align__(16) __half2 qp[16];
#pragma unroll
    for (int i = 0; i < 8; i++) qp[i]     = __floats2half2_rn(qr[2*i], qr[2*i+1]);
#pragma unroll
    for (int i = 0; i < 8; i++) qp[8 + i] = __floats2half2_rn(vr[2*i], vr[2*i+1]);
    float4* qd = (float4*)(qv_h + (size_t)n * 32);
#pragma unroll
    for (int i = 0; i < 4; i++) qd[i] = *(float4*)&qp[4*i];
    float4* sp = (float4*)(skip + (size_t)n * D);
#pragma unroll
    for (int i = 0; i < 4; i++)
        sp[i] = make_float4(hr[4*i], hr[4*i+1], hr[4*i+2], hr[4*i+3]);
}

// ---------------- Kernel B: MFMA edge kernel ----------------
// One wave = 16 edges. MFMA computes E = EA(16x16) @ We(16x16).
// C layout: lane l owns channel c=l&15 of edges wbase + 4*(l>>4) + r (r=reg 0..3).
// MODE bit0: skip k/q/v gathers (synthetic operands). bit1: skip atomic (keep-alive).
template<int MODE>
__global__ void edge_msg_mfma(const int* __restrict__ ei, const float* __restrict__ ea,
                              const float* __restrict__ We,
                              const __half* __restrict__ k_h,
                              const __half* __restrict__ qv_h,
                              __half* __restrict__ hagg,
                              int n_edges, int nlimit) {
    __shared__ __align__(16) int ssrc[64];
    __shared__ __align__(16) int stgt[64];
    int lane = threadIdx.x & 63;
    int wv = threadIdx.x >> 6;          // wave in block: 0..3
    int c = lane & 15;                  // channel
    int g = lane >> 4;                  // lane group: 0..3

    // B fragment: We[k][c], k = 4*g + i  (row-major We[j][c])
    f16x4 bfrag;
#pragma unroll
    for (int i = 0; i < 4; i++) bfrag[i] = (_Float16)We[(4*g + i) * D + c];

    long long blockbase = (long long)blockIdx.x * 64;
    // stage this block's 64 edges' src/tgt (coalesced)
    {
        int t = threadIdx.x;
        if (t < 64) {
            long long e = blockbase + t;
            ssrc[t] = (e < nlimit) ? ei[e] : 0;
        } else if (t < 128) {
            long long e = blockbase + (t - 64);
            stgt[t - 64] = (e < nlimit) ? ei[(size_t)n_edges + e] : 0;
        }
    }
    __syncthreads();

    long long wbase = blockbase + (long long)wv * 16;
    if (wbase >= nlimit) return;

    // A fragment: ea row = wbase + c, cols 4g..4g+3 (one float4, coalesced)
    long long arow = wbase + c;
    if (arow >= nlimit) arow = nlimit - 1;
    float4 av = *(const float4*)(ea + (size_t)arow * D + 4 * g);
    f16x4 afrag = { (_Float16)av.x, (_Float16)av.y, (_Float16)av.z, (_Float16)av.w };

    f32x4 e4 = __builtin_amdgcn_mfma_f32_16x16x16f16(afrag, bfrag, (f32x4){0.f,0.f,0.f,0.f}, 0, 0, 0);

    int le = wv * 16 + 4 * g;           // LDS index of this lane's first owned edge
    int4 src4 = *(const int4*)(ssrc + le);
    int4 tgt4 = *(const int4*)(stgt + le);
    int srcs[4] = { src4.x, src4.y, src4.z, src4.w };
    int tgts[4] = { tgt4.x, tgt4.y, tgt4.z, tgt4.w };

    float msg[4];
#pragma unroll
    for (int r = 0; r < 4; r++) {
        float kk, qq, vv;
        if (!(MODE & 1)) {
            kk = __half2float(k_h[(size_t)tgts[r] * D + c]);
            qq = __half2float(qv_h[(size_t)srcs[r] * 32 + c]);
            vv = __half2float(qv_h[(size_t)srcs[r] * 32 + D + c]);
        } else {
            kk = 0.01f * (float)c; qq = 0.02f * (float)g; vv = 1.0f;
        }
        float z = kk + e4[r] + qq;
        msg[r] = vv / (1.f + __expf(-z));
    }

    if (MODE & 2) {
#pragma unroll
        for (int r = 0; r < 4; r++) asm volatile("" :: "v"(msg[r]));
    } else {
#pragma unroll
        for (int r = 0; r < 4; r++) {
            float partner = __shfl_xor(msg[r], 1);
            long long eidx = wbase + 4 * g + r;
            if (((c & 1) == 0) && eidx < nlimit) {
                __half2 m2 = __floats2half2_rn(msg[r], partner);
                unsafeAtomicAdd((__half2*)&hagg[(size_t)tgts[r] * D + c], m2);
            }
        }
    }
}

// ---------------- Kernel C: BN statistics ----------------
__global__ void bn_stats(const float* __restrict__ skip, const __half* __restrict__ hagg,
                         float* __restrict__ stats, int n_nodes) {
    float s = 0.f, ss = 0.f;
    size_t total = (size_t)n_nodes * D;
    size_t stride = (size_t)gridDim.x * blockDim.x;
    for (size_t i = (size_t)blockIdx.x * blockDim.x + threadIdx.x; i < total; i += stride) {
        float val = skip[i] + __half2float(hagg[i]);
        s += val;
        ss = fmaf(val, val, ss);
    }
    s += __shfl_xor(s, 16); s += __shfl_xor(s, 32);
    ss += __shfl_xor(ss, 16); ss += __shfl_xor(ss, 32);
    __shared__ float ls[4 * D], lss[4 * D];
    int wave = threadIdx.x >> 6, lane = threadIdx.x & 63;
    if (lane < D) { ls[wave * D + lane] = s; lss[wave * D + lane] = ss; }
    __syncthreads();
    if (threadIdx.x < D) {
        float ts = 0.f, tss = 0.f;
#pragma unroll
        for (int w = 0; w < 4; w++) { ts += ls[w * D + threadIdx.x]; tss += lss[w * D + threadIdx.x]; }
        atomicAdd(&stats[threadIdx.x], ts);
        atomicAdd(&stats[D + threadIdx.x], tss);
    }
}

// ---------------- Kernel D: normalize + ReLU + residual ----------------
__global__ void bn_finalize(const float* __restrict__ x, const __half* __restrict__ hagg,
                            const float* __restrict__ stats,
                            const float* __restrict__ gamma, const float* __restrict__ beta,
                            float* __restrict__ out, int n_nodes) {
    __shared__ float sc[D], sh[D];
    if (threadIdx.x < D) {
        float inv_n = 1.f / (float)n_nodes;
        float mean = stats[threadIdx.x] * inv_n;
        float var = stats[D + threadIdx.x] * inv_n - mean * mean;
        float inv = rsqrtf(var + 1e-5f);
        float g = gamma[threadIdx.x] * inv;
        sc[threadIdx.x] = g;
        sh[threadIdx.x] = beta[threadIdx.x] - mean * g;
    }
    __syncthreads();
    size_t i = (size_t)blockIdx.x * blockDim.x + threadIdx.x;
    size_t total = (size_t)n_nodes * D;
    if (i >= total) return;
    int c = (int)(i & (D - 1));
    float h = out[i] + __half2float(hagg[i]);
    float t = fmaf(h, sc[c], sh[c]);
    out[i] = x[i] + fmaxf(t, 0.f);
}

extern "C" void kernel_launch(void* const* d_in, const int* in_sizes, int n_in,
                              void* d_out, int out_size, void* d_ws, size_t ws_size,
                              hipStream_t stream) {
    const float* x     = (const float*)d_in[0];
    const int*   ei    = (const int*)d_in[1];
    const float* ea    = (const float*)d_in[2];
    const float* Wk    = (const float*)d_in[3];
    const float* bk    = (const float*)d_in[4];
    const float* Wq    = (const float*)d_in[5];
    const float* bq    = (const float*)d_in[6];
    const float* Wv    = (const float*)d_in[7];
    const float* bv    = (const float*)d_in[8];
    const float* We    = (const float*)d_in[9];
    const float* Ws    = (const float*)d_in[10];
    const float* bs    = (const float*)d_in[11];
    const float* bias  = (const float*)d_in[12];
    const float* gamma = (const float*)d_in[13];
    const float* beta  = (const float*)d_in[14];

    int n_nodes = in_sizes[0] / D;
    int n_edges = in_sizes[1] / 2;
    float* out = (float*)d_out;

    __half* qv_h = (__half*)d_ws;                       // n*32 f16 (32MB)
    __half* k_h  = qv_h + (size_t)n_nodes * 32;         // n*16 f16 (16MB)
    __half* hagg = k_h + (size_t)n_nodes * D;           // n*16 f16 (16MB)
    float* stats = (float*)(hagg + (size_t)n_nodes * D);

    int nb_nodes = (n_nodes + 255) / 256;
    node_prep<<<nb_nodes, 256, 0, stream>>>(x, Wk, bk, Wq, bq, Wv, bv, Ws, bs, bias,
                                            k_h, qv_h, out, n_nodes);

    // ---- quarter-length ablation probes (diagnostic; hagg garbage, memset after) ----
    int nq = n_edges / 4;
    int nb_q = (nq + 63) / 64;
    edge_msg_mfma<1><<<nb_q, 256, 0, stream>>>(ei, ea, We, k_h, qv_h, hagg, n_edges, nq); // no gathers
    edge_msg_mfma<2><<<nb_q, 256, 0, stream>>>(ei, ea, We, k_h, qv_h, hagg, n_edges, nq); // no atomic
    edge_msg_mfma<3><<<nb_q, 256, 0, stream>>>(ei, ea, We, k_h, qv_h, hagg, n_edges, nq); // floor

    hipMemsetAsync(hagg, 0, (size_t)n_nodes * D * sizeof(__half), stream);
    hipMemsetAsync(stats, 0, 2 * D * sizeof(float), stream);

    // ---- real edge pass ----
    int nb_edges = (n_edges + 63) / 64;
    edge_msg_mfma<0><<<nb_edges, 256, 0, stream>>>(ei, ea, We, k_h, qv_h, hagg, n_edges, n_edges);

    bn_stats<<<2048, 256, 0, stream>>>(out, hagg, stats, n_nodes);

    size_t total = (size_t)n_nodes * D;
    int nb_fin = (int)((total + 255) / 256);
    bn_finalize<<<nb_fin, 256, 0, stream>>>(x, hagg, stats, gamma, beta, out, n_nodes);
}

// Round 7
// 370.550 us; speedup vs baseline: 3.5166x; 1.3729x over previous
//
#include <hip/hip_runtime.h>
#include <hip/hip_bf16.h>
#include <hip/hip_fp16.h>

#define D 16

typedef _Float16 f16x4 __attribute__((ext_vector_type(4)));
typedef float f32x4 __attribute__((ext_vector_type(4)));

// ---------------- Kernel A: per-node linears ----------------
__global__ void node_prep(const float* __restrict__ x,
                          const float* __restrict__ Wk, const float* __restrict__ bk,
                          const float* __restrict__ Wq, const float* __restrict__ bq,
                          const float* __restrict__ Wv, const float* __restrict__ bv,
                          const float* __restrict__ Ws, const float* __restrict__ bs,
                          const float* __restrict__ bias,
                          __half* __restrict__ k_h, __half* __restrict__ qv_h,
                          float* __restrict__ skip, int n_nodes) {
    __shared__ float sWk[D * D], sWq[D * D], sWv[D * D], sWs[D * D], sb[4 * D];
    for (int i = threadIdx.x; i < D * D; i += blockDim.x) {
        sWk[i] = Wk[i]; sWq[i] = Wq[i]; sWv[i] = Wv[i]; sWs[i] = Ws[i];
    }
    if (threadIdx.x < D) {
        sb[threadIdx.x]         = bk[threadIdx.x];
        sb[D + threadIdx.x]     = bq[threadIdx.x];
        sb[2 * D + threadIdx.x] = bv[threadIdx.x];
        sb[3 * D + threadIdx.x] = bs[threadIdx.x] + bias[threadIdx.x];
    }
    __syncthreads();
    int n = blockIdx.x * blockDim.x + threadIdx.x;
    if (n >= n_nodes) return;

    float xr[D];
    const float4* xp = (const float4*)(x + (size_t)n * D);
#pragma unroll
    for (int i = 0; i < 4; i++) {
        float4 t = xp[i];
        xr[4*i] = t.x; xr[4*i+1] = t.y; xr[4*i+2] = t.z; xr[4*i+3] = t.w;
    }
    float kr[D], qr[D], vr[D], hr[D];
#pragma unroll
    for (int c = 0; c < D; c++) {
        kr[c] = sb[c]; qr[c] = sb[D + c]; vr[c] = sb[2*D + c]; hr[c] = sb[3*D + c];
    }
#pragma unroll
    for (int j = 0; j < D; j++) {
        float xj = xr[j];
#pragma unroll
        for (int c = 0; c < D; c++) {
            kr[c] = fmaf(xj, sWk[j * D + c], kr[c]);
            qr[c] = fmaf(xj, sWq[j * D + c], qr[c]);
            vr[c] = fmaf(xj, sWv[j * D + c], vr[c]);
            hr[c] = fmaf(xj, sWs[j * D + c], hr[c]);
        }
    }
    __align__(16) __half2 kp[8];
#pragma unroll
    for (int i = 0; i < 8; i++) kp[i] = __floats2half2_rn(kr[2*i], kr[2*i+1]);
    float4* kd = (float4*)(k_h + (size_t)n * D);
    kd[0] = *(float4*)&kp[0];
    kd[1] = *(float4*)&kp[4];
    __align__(16) __half2 qp[16];
#pragma unroll
    for (int i = 0; i < 8; i++) qp[i]     = __floats2half2_rn(qr[2*i], qr[2*i+1]);
#pragma unroll
    for (int i = 0; i < 8; i++) qp[8 + i] = __floats2half2_rn(vr[2*i], vr[2*i+1]);
    float4* qd = (float4*)(qv_h + (size_t)n * 32);
#pragma unroll
    for (int i = 0; i < 4; i++) qd[i] = *(float4*)&qp[4*i];
    float4* sp = (float4*)(skip + (size_t)n * D);
#pragma unroll
    for (int i = 0; i < 4; i++)
        sp[i] = make_float4(hr[4*i], hr[4*i+1], hr[4*i+2], hr[4*i+3]);
}

// ---------------- Kernel B: MFMA edge kernel ----------------
// One wave = 16 edges. MFMA computes E = EA(16x16) @ We(16x16).
// C layout: lane l owns channel c=l&15 of edges wbase + 4*(l>>4) + r (r=reg 0..3).
// Streaming operands (ea, ei) use non-temporal loads so the k/qv/hagg gather
// working set (64MB) stays L3-resident.
__global__ void edge_msg_mfma(const int* __restrict__ ei, const float* __restrict__ ea,
                              const float* __restrict__ We,
                              const __half* __restrict__ k_h,
                              const __half* __restrict__ qv_h,
                              __half* __restrict__ hagg,
                              int n_edges) {
    __shared__ __align__(16) int ssrc[64];
    __shared__ __align__(16) int stgt[64];
    int lane = threadIdx.x & 63;
    int wv = threadIdx.x >> 6;          // wave in block: 0..3
    int c = lane & 15;                  // channel
    int g = lane >> 4;                  // lane group: 0..3

    // B fragment: We[k][c], k = 4*g + i  (row-major We[j][c])
    f16x4 bfrag;
#pragma unroll
    for (int i = 0; i < 4; i++) bfrag[i] = (_Float16)We[(4*g + i) * D + c];

    long long blockbase = (long long)blockIdx.x * 64;
    // stage this block's 64 edges' src/tgt (coalesced, non-temporal)
    {
        int t = threadIdx.x;
        if (t < 64) {
            long long e = blockbase + t;
            ssrc[t] = (e < n_edges) ? __builtin_nontemporal_load(&ei[e]) : 0;
        } else if (t < 128) {
            long long e = blockbase + (t - 64);
            stgt[t - 64] = (e < n_edges) ? __builtin_nontemporal_load(&ei[(size_t)n_edges + e]) : 0;
        }
    }
    __syncthreads();

    long long wbase = blockbase + (long long)wv * 16;
    if (wbase >= n_edges) return;

    // A fragment: ea row = wbase + c, cols 4g..4g+3 (one float4, coalesced, NT)
    long long arow = wbase + c;
    if (arow >= n_edges) arow = n_edges - 1;
    const float* ap = ea + (size_t)arow * D + 4 * g;
    float av0 = __builtin_nontemporal_load(ap + 0);
    float av1 = __builtin_nontemporal_load(ap + 1);
    float av2 = __builtin_nontemporal_load(ap + 2);
    float av3 = __builtin_nontemporal_load(ap + 3);
    f16x4 afrag = { (_Float16)av0, (_Float16)av1, (_Float16)av2, (_Float16)av3 };

    f32x4 e4 = __builtin_amdgcn_mfma_f32_16x16x16f16(afrag, bfrag, (f32x4){0.f,0.f,0.f,0.f}, 0, 0, 0);

    int le = wv * 16 + 4 * g;           // LDS index of this lane's first owned edge
    int4 src4 = *(const int4*)(ssrc + le);
    int4 tgt4 = *(const int4*)(stgt + le);
    int srcs[4] = { src4.x, src4.y, src4.z, src4.w };
    int tgts[4] = { tgt4.x, tgt4.y, tgt4.z, tgt4.w };

    float msg[4];
#pragma unroll
    for (int r = 0; r < 4; r++) {
        float kk = __half2float(k_h[(size_t)tgts[r] * D + c]);
        float qq = __half2float(qv_h[(size_t)srcs[r] * 32 + c]);
        float vv = __half2float(qv_h[(size_t)srcs[r] * 32 + D + c]);
        float z = kk + e4[r] + qq;
        msg[r] = vv / (1.f + __expf(-z));
    }

#pragma unroll
    for (int r = 0; r < 4; r++) {
        float partner = __shfl_xor(msg[r], 1);
        long long eidx = wbase + 4 * g + r;
        if (((c & 1) == 0) && eidx < n_edges) {
            __half2 m2 = __floats2half2_rn(msg[r], partner);
            unsafeAtomicAdd((__half2*)&hagg[(size_t)tgts[r] * D + c], m2);
        }
    }
}

// ---------------- Kernel C: BN statistics ----------------
__global__ void bn_stats(const float* __restrict__ skip, const __half* __restrict__ hagg,
                         float* __restrict__ stats, int n_nodes) {
    float s = 0.f, ss = 0.f;
    size_t total = (size_t)n_nodes * D;
    size_t stride = (size_t)gridDim.x * blockDim.x;
    for (size_t i = (size_t)blockIdx.x * blockDim.x + threadIdx.x; i < total; i += stride) {
        float val = skip[i] + __half2float(hagg[i]);
        s += val;
        ss = fmaf(val, val, ss);
    }
    s += __shfl_xor(s, 16); s += __shfl_xor(s, 32);
    ss += __shfl_xor(ss, 16); ss += __shfl_xor(ss, 32);
    __shared__ float ls[4 * D], lss[4 * D];
    int wave = threadIdx.x >> 6, lane = threadIdx.x & 63;
    if (lane < D) { ls[wave * D + lane] = s; lss[wave * D + lane] = ss; }
    __syncthreads();
    if (threadIdx.x < D) {
        float ts = 0.f, tss = 0.f;
#pragma unroll
        for (int w = 0; w < 4; w++) { ts += ls[w * D + threadIdx.x]; tss += lss[w * D + threadIdx.x]; }
        atomicAdd(&stats[threadIdx.x], ts);
        atomicAdd(&stats[D + threadIdx.x], tss);
    }
}

// ---------------- Kernel D: normalize + ReLU + residual ----------------
__global__ void bn_finalize(const float* __restrict__ x, const __half* __restrict__ hagg,
                            const float* __restrict__ stats,
                            const float* __restrict__ gamma, const float* __restrict__ beta,
                            float* __restrict__ out, int n_nodes) {
    __shared__ float sc[D], sh[D];
    if (threadIdx.x < D) {
        float inv_n = 1.f / (float)n_nodes;
        float mean = stats[threadIdx.x] * inv_n;
        float var = stats[D + threadIdx.x] * inv_n - mean * mean;
        float inv = rsqrtf(var + 1e-5f);
        float g = gamma[threadIdx.x] * inv;
        sc[threadIdx.x] = g;
        sh[threadIdx.x] = beta[threadIdx.x] - mean * g;
    }
    __syncthreads();
    size_t i = (size_t)blockIdx.x * blockDim.x + threadIdx.x;
    size_t total = (size_t)n_nodes * D;
    if (i >= total) return;
    int c = (int)(i & (D - 1));
    float h = out[i] + __half2float(hagg[i]);
    float t = fmaf(h, sc[c], sh[c]);
    out[i] = x[i] + fmaxf(t, 0.f);
}

extern "C" void kernel_launch(void* const* d_in, const int* in_sizes, int n_in,
                              void* d_out, int out_size, void* d_ws, size_t ws_size,
                              hipStream_t stream) {
    const float* x     = (const float*)d_in[0];
    const int*   ei    = (const int*)d_in[1];
    const float* ea    = (const float*)d_in[2];
    const float* Wk    = (const float*)d_in[3];
    const float* bk    = (const float*)d_in[4];
    const float* Wq    = (const float*)d_in[5];
    const float* bq    = (const float*)d_in[6];
    const float* Wv    = (const float*)d_in[7];
    const float* bv    = (const float*)d_in[8];
    const float* We    = (const float*)d_in[9];
    const float* Ws    = (const float*)d_in[10];
    const float* bs    = (const float*)d_in[11];
    const float* bias  = (const float*)d_in[12];
    const float* gamma = (const float*)d_in[13];
    const float* beta  = (const float*)d_in[14];

    int n_nodes = in_sizes[0] / D;
    int n_edges = in_sizes[1] / 2;
    float* out = (float*)d_out;

    __half* qv_h = (__half*)d_ws;                       // n*32 f16 (32MB)
    __half* k_h  = qv_h + (size_t)n_nodes * 32;         // n*16 f16 (16MB)
    __half* hagg = k_h + (size_t)n_nodes * D;           // n*16 f16 (16MB)
    float* stats = (float*)(hagg + (size_t)n_nodes * D);

    hipMemsetAsync(hagg, 0, (size_t)n_nodes * D * sizeof(__half), stream);
    hipMemsetAsync(stats, 0, 2 * D * sizeof(float), stream);

    int nb_nodes = (n_nodes + 255) / 256;
    node_prep<<<nb_nodes, 256, 0, stream>>>(x, Wk, bk, Wq, bq, Wv, bv, Ws, bs, bias,
                                            k_h, qv_h, out, n_nodes);

    int nb_edges = (n_edges + 63) / 64;
    edge_msg_mfma<<<nb_edges, 256, 0, stream>>>(ei, ea, We, k_h, qv_h, hagg, n_edges);

    bn_stats<<<2048, 256, 0, stream>>>(out, hagg, stats, n_nodes);

    size_t total = (size_t)n_nodes * D;
    int nb_fin = (int)((total + 255) / 256);
    bn_finalize<<<nb_fin, 256, 0, stream>>>(x, hagg, stats, gamma, beta, out, n_nodes);
}